// Round 12
// baseline (142.476 us; speedup 1.0000x reference)
//
#include <hip/hip_runtime.h>
#include <hip/hip_bf16.h>
#include <math.h>

#define DEVFN __device__ __forceinline__

typedef __attribute__((ext_vector_type(8))) __bf16 bf16x8;
typedef __attribute__((ext_vector_type(8))) short s16x8;
typedef __attribute__((ext_vector_type(4))) float f32x4;
typedef __attribute__((ext_vector_type(16))) float f32x16;
typedef __attribute__((ext_vector_type(4))) unsigned int u32x4;

constexpr int Tt    = 2048;
constexpr int INt   = 128;
constexpr int Ht    = 256;
constexpr int OUTt  = 8;
constexpr int TT    = 32;           // time tile
constexpr int NTILE = 64;

union Frag {
  s16x8 s;
  bf16x8 b;
  u32x4 u;
};

DEVFN unsigned short f2bf(float f) {
  unsigned int u = __builtin_bit_cast(unsigned int, f);
  u += 0x7fffu + ((u >> 16) & 1u);   // round-to-nearest-even
  return (unsigned short)(u >> 16);
}

DEVFN unsigned int pack2(float lo, float hi) {
  return (unsigned int)f2bf(lo) | ((unsigned int)f2bf(hi) << 16);
}

typedef __attribute__((address_space(3))) unsigned int lds_u32;
typedef const __attribute__((address_space(1))) unsigned int glb_u32;

// HBM -> LDS DMA, 16B/lane, LDS dest = uniform base + lane*16 (linear).
DEVFN void dma16(const float* g, const float* l) {
  __builtin_amdgcn_global_load_lds((glb_u32*)(uintptr_t)g,
                                   (lds_u32*)(unsigned int)(uintptr_t)l,
                                   16, 0, 0);
}

__global__
__attribute__((amdgpu_flat_work_group_size(1024, 1024)))
void sfnn_fused(
    const float* __restrict__ x, const float* __restrict__ Wb,
    const float* __restrict__ bb, const float* __restrict__ Wo,
    const float* __restrict__ bo, const float* __restrict__ tau_m,
    const float* __restrict__ tau_n, float* __restrict__ out)
{
  const int b    = blockIdx.x;
  const int tid  = threadIdx.x;
  const int lane = tid & 63;
  const int w    = tid >> 6;          // wave id 0..15
  const int l16  = lane & 15;
  const int lhi  = lane >> 4;
  const int l32  = lane & 31;
  const int uh   = lane >> 5;

  // LDS: 32K Xraw + 16K Xb + 64K DfT + 32K Mb = 144KB
  __shared__ __align__(16) float          Xraw[2][TT * INt];   // DMA dest, linear f32
  __shared__ __align__(16) unsigned char  Xb[2][TT * 256];     // bf16 x, swizzled
  __shared__ __align__(16) float          DfT[2][Ht * TT];     // D^T f32 [h][t], swz
  __shared__ __align__(16) unsigned short Mb[2][TT * Ht];      // m bf16 [t][h], swz

  // ---- GEMM waves 0-7: branch weights (B operand, 32x32x16), r9-verified ----
  const int ch = (32 * w + l32) & 255;
  Frag Wf[8];
  if (w < 8) {
    const int n = ch >> 6, s = ch & 63;
    #pragma unroll
    for (int ks = 0; ks < 8; ++ks) {
      #pragma unroll
      for (int j = 0; j < 8; ++j) {
        const int i = 16 * ks + 8 * uh + j;
        Wf[ks].s[j] = (short)f2bf(Wb[(n * 128 + i) * 64 + s]);
      }
    }
  }

  // ---- proj waves 10-11: Wo fragments in registers (B operand, 16x16x32) ----
  Frag WoF[8];
  if (w >= 10 && w < 12) {
    #pragma unroll
    for (int ks = 0; ks < 8; ++ks) {
      #pragma unroll
      for (int j = 0; j < 8; ++j) {
        const int kk = 32 * ks + 8 * lhi + j;
        const float v = (l16 < OUTt) ? Wo[kk * OUTt + l16] : 0.f;
        WoF[ks].s[j] = (short)f2bf(v);
      }
    }
  }
  const float bo_l = (l16 < OUTt) ? bo[l16] : 0.f;

  // ---- scan waves 8-9: params for 2 channels (ch0=128v+2L, ch1=ch0+1) ----
  float be0=0,om0=0,al0=0,oa0=0,bb0=0, be1=0,om1=0,al1=0,oa1=0,bb1=0;
  if (w == 8 || w == 9) {
    const int ch0 = 128 * (w - 8) + 2 * lane;
    be0 = 1.f/(1.f+expf(-tau_n[ch0]));   om0 = 1.f - be0;
    al0 = 1.f/(1.f+expf(-tau_m[ch0]));   oa0 = 1.f - al0;
    bb0 = bb[ch0];
    be1 = 1.f/(1.f+expf(-tau_n[ch0+1])); om1 = 1.f - be1;
    al1 = 1.f/(1.f+expf(-tau_m[ch0+1])); oa1 = 1.f - al1;
    bb1 = bb[ch0+1];
  }

  const float* xb   = x   + (size_t)b * Tt * INt;
  float*       outb = out + (size_t)b * Tt * OUTt;

  float  c0 = 0.f, m0 = 0.f, c1 = 0.f, m1 = 0.f;  // scan state
  f32x16 dacc;                                     // GEMM accumulator

  #define BAR() do {                                                       \
    asm volatile("s_waitcnt lgkmcnt(0)" ::: "memory");                     \
    __builtin_amdgcn_s_barrier();                                          \
  } while (0)

  #define WAITVM(N) do {                                                   \
    asm volatile("s_waitcnt vmcnt(" #N ")" ::: "memory");                  \
    __builtin_amdgcn_sched_barrier(0);                                     \
  } while (0)

  // stager waves 12-15: wave DMAs its own 4 chunks of 1KB (r8 pattern)
  #define ISSUE_DMA(TILE) do {                                             \
    const int _bi = (TILE) & 1;                                            \
    const float* _gs = xb + (size_t)(TILE) * (TT * INt);                   \
    _Pragma("unroll")                                                      \
    for (int q = 0; q < 4; ++q) {                                          \
      const int c = (w - 12) * 4 + q;                                      \
      dma16(_gs + c * 256 + lane * 4, &Xraw[_bi][c * 256]);                \
    }                                                                      \
  } while (0)

  // wave converts EXACTLY the chunks it DMA'd (per-wave vmcnt covers them).
  #define CONVERT(TILE) do {                                               \
    const int _bi = (TILE) & 1;                                            \
    const int i8  = 8 * (lane & 31);                                       \
    _Pragma("unroll")                                                      \
    for (int q = 0; q < 4; ++q) {                                          \
      const int c = (w - 12) * 4 + q;                                      \
      const int t = 2 * c + (lane >> 5);                                   \
      f32x4 v = *(const f32x4*)(&Xraw[_bi][256 * c + 4 * lane]);           \
      unsigned long long pk = (unsigned long long)pack2(v[0], v[1]) |      \
            ((unsigned long long)pack2(v[2], v[3]) << 32);                 \
      *(unsigned long long*)(&Xb[_bi][t * 256 + (i8 ^ ((t & 7) << 4))]) = pk; \
    }                                                                      \
  } while (0)

  // GEMM: D[t 0..32)[h 32w..+32), K=128, 8x mfma 32x32x16 (r9-verified)
  #define GEMMZ(BUF) do {                                                  \
    _Pragma("unroll")                                                      \
    for (int ri = 0; ri < 16; ++ri) dacc[ri] = 0.f;                        \
    const int rs = l32 * 256, sw = (l32 & 7) << 4;                         \
    _Pragma("unroll")                                                      \
    for (int ks = 0; ks < 8; ++ks) {                                       \
      Frag a;                                                              \
      a.u = *(const u32x4*)(&Xb[BUF][rs + ((32 * ks + 16 * uh) ^ sw)]);    \
      dacc = __builtin_amdgcn_mfma_f32_32x32x16_bf16(a.b, Wf[ks].b, dacc, 0, 0, 0); \
    }                                                                      \
  } while (0)

  // dacc -> DfT[h][t] f32, b128 per t-quad (2g+uh), slot XOR s=(h>>1)&7
  // C/D row t' = (reg&3) + 8*(reg>>2) + 4*uh -> quad (2g+uh) holds t 8g+4uh+r
  #define WRITEDF(BUF) do {                                                \
    const int hb = (32 * w + l32) * 32;                                    \
    const int sdw = (l32 >> 1) & 7;                                        \
    _Pragma("unroll")                                                      \
    for (int g = 0; g < 4; ++g) {                                          \
      f32x4 qv = f32x4{dacc[4*g], dacc[4*g+1], dacc[4*g+2], dacc[4*g+3]};  \
      *(f32x4*)(&DfT[BUF][hb + 4 * ((2 * g + uh) ^ sdw)]) = qv;            \
    }                                                                      \
  } while (0)

  // scan waves 8-9: 2 ch/lane, ALL 8 quads per channel (r11 fix: was 4),
  // logical quad q stored at slot q^sL; t = 4q+r ascending.
  #define SCAN(BUF) do {                                                   \
    const int vv = w - 8;                                                  \
    const int ch0b = (128 * vv + 2 * lane) * 32;                           \
    const int sL = lane & 7;                                               \
    const int mcol = ((16 * vv + (lane >> 2)) & 31);                       \
    _Pragma("unroll")                                                      \
    for (int q = 0; q < 8; ++q) {                                          \
      f32x4 dv0 = *(const f32x4*)(&DfT[BUF][ch0b + 4 * (q ^ sL)]);         \
      f32x4 dv1 = *(const f32x4*)(&DfT[BUF][ch0b + 32 + 4 * (q ^ sL)]);    \
      _Pragma("unroll")                                                    \
      for (int r = 0; r < 4; ++r) {                                        \
        const int t = 4 * q + r;                                           \
        const float d0 = dv0[r] + bb0;                                     \
        c0 = fmaf(be0, c0, om0 * d0);                                      \
        m0 = fmaf(al0, m0, oa0 * c0);                                      \
        const float d1 = dv1[r] + bb1;                                     \
        c1 = fmaf(be1, c1, om1 * d1);                                      \
        m1 = fmaf(al1, m1, oa1 * c1);                                      \
        *(unsigned int*)(&Mb[BUF][t * 256 + ((mcol ^ (t & 7)) << 3) + 2 * (lane & 3)]) \
            = pack2(m0, m1);                                               \
      }                                                                    \
    }                                                                      \
  } while (0)

  // proj waves 10-11: 16 t-rows each, K=256, WoF in regs, sigmoid + store
  #define PROJ(TI, BUF) do {                                               \
    const int pw = w - 10;                                                 \
    const int trow = 16 * pw + l16;                                        \
    const int mrb = trow * 256, msw = trow & 7;                            \
    f32x4 p = f32x4{0.f, 0.f, 0.f, 0.f};                                   \
    _Pragma("unroll")                                                      \
    for (int ks = 0; ks < 8; ++ks) {                                       \
      Frag ma;                                                             \
      ma.u = *(const u32x4*)(&Mb[BUF][mrb + (((4 * ks + lhi) ^ msw) << 3)]); \
      p = __builtin_amdgcn_mfma_f32_16x16x32_bf16(ma.b, WoF[ks].b, p, 0, 0, 0); \
    }                                                                      \
    if (l16 < OUTt) {                                                      \
      _Pragma("unroll")                                                    \
      for (int r = 0; r < 4; ++r) {                                        \
        const int t = 16 * pw + 4 * lhi + r;                               \
        outb[(size_t)((TI) * TT + t) * OUTt + l16] =                       \
            1.f / (1.f + __expf(-(p[r] + bo_l)));                          \
      }                                                                    \
    }                                                                      \
  } while (0)

  // one barrier per iter; roles fully disjoint by wave.
  #define ITER(J, DOG, DOS, DOP, ISS_STMT, WAIT_STMT, CVT_STMT) do {       \
    if (w < 8)       { if (DOG) { GEMMZ((J) & 1); WRITEDF((J) & 1); } }    \
    else if (w < 10) { if (DOS) SCAN(((J) - 1) & 1); }                     \
    else if (w < 12) { if (DOP) PROJ((J) - 2, (J) & 1); }                  \
    else             { ISS_STMT; WAIT_STMT; CVT_STMT; }                    \
    BAR();                                                                 \
  } while (0)

  // ---------------- prologue ----------------
  if (w >= 12) {
    ISSUE_DMA(0);
    ISSUE_DMA(1);                      // 8 outstanding (own)
    WAITVM(4);                         // own tile-0 chunks landed
    CONVERT(0);                        // Xb[0]
  }
  BAR();

  // ---------------- pipeline: J = 0..65 ----------------
  ITER(0, 1, 0, 0, ISSUE_DMA(2), WAITVM(4), CONVERT(1));
  ITER(1, 1, 1, 0, ISSUE_DMA(3), WAITVM(4), CONVERT(2));
  for (int jj = 1; jj <= 29; ++jj) {
    const int J = 2 * jj;
    ITER(J,     1, 1, 1, ISSUE_DMA(J + 2), WAITVM(4), CONVERT(J + 1));
    ITER(J + 1, 1, 1, 1, ISSUE_DMA(J + 3), WAITVM(4), CONVERT(J + 2));
  }
  ITER(60, 1, 1, 1, ISSUE_DMA(62), WAITVM(4), CONVERT(61));
  ITER(61, 1, 1, 1, ISSUE_DMA(63), WAITVM(4), CONVERT(62));
  ITER(62, 1, 1, 1, (void)0, WAITVM(0), CONVERT(63));
  ITER(63, 1, 1, 1, (void)0, (void)0, (void)0);
  ITER(64, 0, 1, 1, (void)0, (void)0, (void)0);
  ITER(65, 0, 0, 1, (void)0, (void)0, (void)0);

  #undef ISSUE_DMA
  #undef CONVERT
  #undef GEMMZ
  #undef WRITEDF
  #undef SCAN
  #undef PROJ
  #undef ITER
  #undef BAR
  #undef WAITVM
}

extern "C" void kernel_launch(void* const* d_in, const int* in_sizes, int n_in,
                              void* d_out, int out_size, void* d_ws, size_t ws_size,
                              hipStream_t stream) {
  const float* x     = (const float*)d_in[0];
  const float* Wb    = (const float*)d_in[1];
  const float* bb    = (const float*)d_in[2];
  const float* Wo    = (const float*)d_in[3];
  const float* bo    = (const float*)d_in[4];
  const float* tau_m = (const float*)d_in[5];
  const float* tau_n = (const float*)d_in[6];
  float* out = (float*)d_out;

  sfnn_fused<<<dim3(256), dim3(1024), 0, stream>>>(x, Wb, bb, Wo, bo, tau_m, tau_n, out);
}